// Round 6
// baseline (299.087 us; speedup 1.0000x reference)
//
#include <hip/hip_runtime.h>
#include <hip/hip_fp16.h>
#include <math.h>

constexpr int N = 20000, D = 256, E = 320000, B = 2, L = 2;
constexpr int CAP = 64;  // slot capacity per node; Poisson(16) max over 40000 draws ~45

typedef _Float16 f16x8 __attribute__((ext_vector_type(8)));
typedef float f32x4 __attribute__((ext_vector_type(4)));

__device__ __forceinline__ unsigned short f2h(float f) {
  __half h = __float2half(f);  // RNE, v_cvt_f16_f32
  return *(unsigned short*)&h;
}
__device__ __forceinline__ float2 h2f(unsigned int u) {
  __half2 hv = *reinterpret_cast<__half2*>(&u);
  return __half22float2(hv);
}

// ---------------- prep: W transpose->fp16, wa = W@a[:D], zero sn0/sn1/deg -------------
// blocks 0..511: wt (l = bi>>8, 16x16 tile transpose)
// blocks 512..513: wa (l = bi-512)
// blocks 514..631: zero 30000 uint4 (sn0,sn1,deg contiguous = 120000 words)
__global__ __launch_bounds__(256) void prep_kernel(const float* __restrict__ W,
                                                   const float* __restrict__ a,
                                                   unsigned short* __restrict__ Wt,
                                                   float* __restrict__ wa,
                                                   uint4* __restrict__ zbase) {
  int bi = blockIdx.x, tid = threadIdx.x;
  if (bi < 512) {
    __shared__ float t[16][17];
    int l = bi >> 8, rem = bi & 255;
    int by = rem >> 4, bx = rem & 15;  // by: k block, bx: n block
    int tx = tid & 15, ty = tid >> 4;
    t[ty][tx] = W[l * 65536 + (by * 16 + ty) * 256 + bx * 16 + tx];
    __syncthreads();
    Wt[l * 65536 + (bx * 16 + ty) * 256 + by * 16 + tx] = f2h(t[tx][ty]);
  } else if (bi < 514) {
    int l = bi - 512;
    float s = 0.f;
    for (int d = 0; d < D; ++d) s += W[l * 65536 + tid * D + d] * a[l * 2 * D + d];
    wa[l * D + tid] = s;
  } else {
    int zi = (bi - 514) * 256 + tid;
    if (zi < 30000) zbase[zi] = make_uint4(0, 0, 0, 0);
  }
}

// ------- fused slot-scatter (adjacency build, 4 edges/thread ILP) + sq (xq . wa) -------
// blocks 0..624: slot scatter (atomics earliest; 4 independent atomic chains/thread)
// blocks 625..10624: sq (one wave per node)
__global__ __launch_bounds__(256) void tsc_kernel(const float* __restrict__ xq,
                                                  const float* __restrict__ wa,
                                                  float* __restrict__ sq,
                                                  const int* __restrict__ edges,
                                                  int* __restrict__ deg,
                                                  int* __restrict__ slot) {
  int bi = blockIdx.x, tid = threadIdx.x;
  if (bi < 625) {
    int ebase = bi * 1024 + tid;  // 625*1024 = B*E = 640,000 exact
    int s4[4], d4[4];
#pragma unroll
    for (int q = 0; q < 4; ++q) {
      int e = ebase + q * 256;
      int b = (e >= E) ? 1 : 0;
      s4[q] = edges[(size_t)b * E + e];
      d4[q] = edges[(size_t)(b + 1) * E + e];
    }
#pragma unroll
    for (int q = 0; q < 4; ++q) {
      int e = ebase + q * 256;
      int b = (e >= E) ? 1 : 0;
      int nb = b * N + s4[q];
      int pos = atomicAdd(&deg[nb], 1);
      if (pos < CAP) slot[((size_t)nb << 6) + pos] = d4[q];
    }
  } else {
    int sqb = bi - 625;
    int b = (sqb >= 5000) ? 1 : 0;
    int blk = sqb - b * 5000;
    int wave = blk * 4 + (tid >> 6);
    int lane = tid & 63;
    const float4 xv = *(const float4*)(xq + ((size_t)b * N + wave) * D + (lane << 2));
    const float4 w0 = *(const float4*)(wa + (lane << 2));
    const float4 w1 = *(const float4*)(wa + D + (lane << 2));
    float s0 = xv.x * w0.x + xv.y * w0.y + xv.z * w0.z + xv.w * w0.w;
    float s1 = xv.x * w1.x + xv.y * w1.y + xv.z * w1.z + xv.w * w1.w;
    for (int off = 32; off; off >>= 1) {
      s0 += __shfl_down(s0, off);
      s1 += __shfl_down(s1, off);
    }
    if (lane == 0) {
      sq[(b * 2 + 0) * N + wave] = s0;
      sq[(b * 2 + 1) * N + wave] = s1;
    }
  }
}

// ---------------- MFMA GEMM (both batches, fp16): Ch = A @ W (fp16 out), fused sn ---------
// F32A=true: A is raw f32 nodes, converted to fp16 in-register during LDS staging.
// F32A=false: A is fp16 (h1). Entire matmul pipeline is fp16 (10-bit mantissa):
// 8x less rounding error than bf16, same MFMA rate on gfx950, fp16 range is ample
// (|x|<6, |W|<0.6, |h|<10; accumulation in f32).
template <bool F32A>
__global__ __launch_bounds__(256) void gemm_mfma(const void* __restrict__ Av,
                                                 const unsigned short* __restrict__ Wt,
                                                 unsigned short* __restrict__ Ch,
                                                 const float* __restrict__ a2,
                                                 float* __restrict__ sn, int M) {
  __shared__ unsigned short As[128 * 32];  // [m][k]
  __shared__ unsigned short Bs[64 * 32];   // [n][k]
  int z = blockIdx.z;
  unsigned short* Cz = Ch + (size_t)z * M * 256;
  float* snz = sn + (size_t)z * M;
  int tid = threadIdx.x;
  int bm = blockIdx.y * 128, bn = blockIdx.x * 64;
  int wv = tid >> 6, lane = tid & 63;
  int lm = lane & 15, lq = lane >> 4;
  f32x4 acc[2][4] = {};

  for (int k0 = 0; k0 < 256; k0 += 32) {
    int m = tid >> 1, kb = (tid & 1) << 4;
    if (bm + m < M) {
      if constexpr (F32A) {
        const float* ap = (const float*)Av + (size_t)z * M * 256 + (size_t)(bm + m) * 256 + k0 + kb;
        float4 v0 = ((const float4*)ap)[0];
        float4 v1 = ((const float4*)ap)[1];
        float4 v2 = ((const float4*)ap)[2];
        float4 v3 = ((const float4*)ap)[3];
        unsigned short t[16] = {f2h(v0.x), f2h(v0.y), f2h(v0.z), f2h(v0.w),
                                f2h(v1.x), f2h(v1.y), f2h(v1.z), f2h(v1.w),
                                f2h(v2.x), f2h(v2.y), f2h(v2.z), f2h(v2.w),
                                f2h(v3.x), f2h(v3.y), f2h(v3.z), f2h(v3.w)};
        *(uint4*)&As[m * 32 + kb] = *(uint4*)t;
        *(uint4*)&As[m * 32 + kb + 8] = *(uint4*)(t + 8);
      } else {
        const unsigned short* ap =
            (const unsigned short*)Av + (size_t)z * M * 256 + (size_t)(bm + m) * 256 + k0 + kb;
        *(uint4*)&As[m * 32 + kb] = *(const uint4*)ap;
        *(uint4*)&As[m * 32 + kb + 8] = *(const uint4*)(ap + 8);
      }
    } else {
      uint4 z4 = make_uint4(0, 0, 0, 0);
      *(uint4*)&As[m * 32 + kb] = z4;
      *(uint4*)&As[m * 32 + kb + 8] = z4;
    }
    int nn = tid >> 2, kb2 = (tid & 3) << 3;
    *(uint4*)&Bs[nn * 32 + kb2] = *(const uint4*)(Wt + (size_t)(bn + nn) * 256 + k0 + kb2);
    __syncthreads();

    f16x8 af0 = *(const f16x8*)&As[(wv * 32 + lm) * 32 + lq * 8];
    f16x8 af1 = *(const f16x8*)&As[(wv * 32 + 16 + lm) * 32 + lq * 8];
#pragma unroll
    for (int nf = 0; nf < 4; ++nf) {
      f16x8 bfr = *(const f16x8*)&Bs[(nf * 16 + lm) * 32 + lq * 8];
      acc[0][nf] = __builtin_amdgcn_mfma_f32_16x16x32_f16(af0, bfr, acc[0][nf], 0, 0, 0);
      acc[1][nf] = __builtin_amdgcn_mfma_f32_16x16x32_f16(af1, bfr, acc[1][nf], 0, 0, 0);
    }
    __syncthreads();
  }

  float a2v[4];
#pragma unroll
  for (int nf = 0; nf < 4; ++nf) a2v[nf] = a2[bn + nf * 16 + lm];
#pragma unroll
  for (int f = 0; f < 2; ++f) {
#pragma unroll
    for (int r = 0; r < 4; ++r) {
      int row = bm + wv * 32 + f * 16 + lq * 4 + r;
      if (row < M) {
        float partial = 0.f;
#pragma unroll
        for (int nf = 0; nf < 4; ++nf) {
          float v = acc[f][nf][r];
          Cz[(size_t)row * 256 + bn + nf * 16 + lm] = f2h(v);  // fp16 intermediate
          partial += v * a2v[nf];
        }
        partial += __shfl_xor(partial, 1);
        partial += __shfl_xor(partial, 2);
        partial += __shfl_xor(partial, 4);
        partial += __shfl_xor(partial, 8);
        if (lm == 0) atomicAdd(&snz[row], partial);
      }
    }
  }
}

// ---------------- fused weight + aggregation: ONE WAVE per node, slot table ----------
// deg <= 64 always -> single chunk, no outer loop. 4 nodes per 256-thread block,
// no LDS/barriers. h-row gathers issued from slot idx alone (batch of 4, double-
// buffered), sn-gather -> exp chain computes in their shadow. h and h1 are fp16.
__global__ __launch_bounds__(256) void agg_kernel(const int* __restrict__ deg,
                                                  const int* __restrict__ slot,
                                                  const float* __restrict__ sq_all,
                                                  const float* __restrict__ sn,
                                                  const unsigned short* __restrict__ hhf,
                                                  const float* __restrict__ resid,
                                                  float* __restrict__ outf,
                                                  unsigned short* __restrict__ outh, int l) {
  int b = blockIdx.y;
  int tid = threadIdx.x, wv = tid >> 6, lane = tid & 63;
  int node = blockIdx.x * 4 + wv;
  int eg = lane >> 5, dl = lane & 31;
  const float* snb = sn + (size_t)b * N;
  const unsigned short* hb = hhf + (size_t)b * N * 256;
  int nb = b * N + node;
  int cnt = min(deg[nb], CAP);
  const int* sl = slot + ((size_t)nb << 6);
  float sqv = sq_all[((b << 1) + l) * N + node];
  int idx = 0;
  float snv = 0.f;
  if (lane < cnt) {
    idx = sl[lane];
    snv = snb[idx];
  }
  int nj = (cnt - eg + 1) >> 1;  // edges this half-wave handles (j = eg, eg+2, ...)
  // issue first gather batch from idx alone (overlaps the snv/exp chain below)
  uint4 hv[4];
#pragma unroll
  for (int u = 0; u < 4; ++u) {
    int dsti = __shfl(idx, eg + 2 * u);  // <= 7, in range
    if (u < nj) hv[u] = *(const uint4*)(hb + (size_t)dsti * 256 + (dl << 3));
  }
  float s = sqv + snv;
  float lr = (s >= 0.f) ? s : 0.2f * s;
  float w = (lane < cnt) ? __expf(-lr) : 0.f;
  float wsum = w;
  float acc[8] = {};
  for (int u0 = 0; u0 < nj; u0 += 4) {
    uint4 hn[4];
#pragma unroll
    for (int u = 0; u < 4; ++u) {  // prefetch next batch
      int uu = u0 + 4 + u;
      int js = eg + 2 * uu;
      js = (js < 63) ? js : 63;  // clamp (result unused when uu >= nj)
      int dsti = __shfl(idx, js);
      if (uu < nj) hn[u] = *(const uint4*)(hb + (size_t)dsti * 256 + (dl << 3));
    }
#pragma unroll
    for (int u = 0; u < 4; ++u) {
      int uu = u0 + u;
      if (uu < nj) {
        float wj = __shfl(w, eg + 2 * uu);
        float2 f0 = h2f(hv[u].x), f1 = h2f(hv[u].y), f2 = h2f(hv[u].z), f3 = h2f(hv[u].w);
        acc[0] = fmaf(wj, f0.x, acc[0]);
        acc[1] = fmaf(wj, f0.y, acc[1]);
        acc[2] = fmaf(wj, f1.x, acc[2]);
        acc[3] = fmaf(wj, f1.y, acc[3]);
        acc[4] = fmaf(wj, f2.x, acc[4]);
        acc[5] = fmaf(wj, f2.y, acc[5]);
        acc[6] = fmaf(wj, f3.x, acc[6]);
        acc[7] = fmaf(wj, f3.y, acc[7]);
      }
    }
#pragma unroll
    for (int u = 0; u < 4; ++u) hv[u] = hn[u];
  }
  // full-wave rowsum (same value in every lane)
  for (int off = 32; off; off >>= 1) wsum += __shfl_xor(wsum, off);
  // merge the two half-wave edge partitions; every lane ends with the full sum
#pragma unroll
  for (int i = 0; i < 8; ++i) acc[i] += __shfl_xor(acc[i], 32);
  float inv = (wsum > 0.f) ? 1.f / wsum : 0.f;
  float o0 = (eg ? acc[4] : acc[0]) * inv;
  float o1 = (eg ? acc[5] : acc[1]) * inv;
  float o2 = (eg ? acc[6] : acc[2]) * inv;
  float o3 = (eg ? acc[7] : acc[3]) * inv;
  size_t rowoff = ((size_t)b * N + node) * 256 + (dl << 3) + (eg << 2);
  if (outh) {
    unsigned short t[4] = {f2h(o0), f2h(o1), f2h(o2), f2h(o3)};
    *(uint2*)(outh + rowoff) = *(uint2*)t;
  } else {
    const float4 rv = *(const float4*)(resid + rowoff);
    *(float4*)(outf + rowoff) = make_float4(o0 + rv.x, o1 + rv.y, o2 + rv.z, o3 + rv.w);
  }
}

extern "C" void kernel_launch(void* const* d_in, const int* in_sizes, int n_in,
                              void* d_out, int out_size, void* d_ws, size_t ws_size,
                              hipStream_t stream) {
  const float* nodes = (const float*)d_in[0];
  const float* nodesq = (const float*)d_in[1];
  const float* W = (const float*)d_in[2];
  const float* a = (const float*)d_in[3];
  const int* edges = (const int*)d_in[4];
  float* out = (float*)d_out;

  const size_t ND = (size_t)N * D;
  unsigned short* hhf = (unsigned short*)d_ws;  // B*N*D  (GEMM output h_proj, fp16)
  unsigned short* h1hf = hhf + (size_t)B * ND;  // B*N*D  (layer-0 agg output, fp16)
  unsigned short* Wt = h1hf + (size_t)B * ND;   // L*D*D (fp16)
  // contiguous zero region: sn0, sn1, deg  (3 x 40000 words = 30000 uint4)
  float* sn0 = (float*)(Wt + (size_t)L * D * D);  // B*N
  float* sn1 = sn0 + B * N;                       // B*N
  int* deg = (int*)(sn1 + B * N);                 // B*N
  float* sq_all = (float*)(deg + B * N);          // B*L*N
  float* wa = sq_all + (size_t)B * L * N;         // L*D
  int* slot = (int*)(wa + L * D);                 // B*N*CAP ints (10.24 MB)

  prep_kernel<<<632, 256, 0, stream>>>(W, a, Wt, wa, (uint4*)sn0);
  tsc_kernel<<<10625, 256, 0, stream>>>(nodesq, wa, sq_all, edges, deg, slot);

  for (int l = 0; l < L; ++l) {
    const float* al2 = a + (size_t)l * 2 * D + D;
    float* snl = (l == 0) ? sn0 : sn1;
    bool last = (l == L - 1);
    if (l == 0) {
      gemm_mfma<true><<<dim3(4, (N + 127) / 128, B), 256, 0, stream>>>(
          nodes, Wt, hhf, al2, snl, N);
    } else {
      gemm_mfma<false><<<dim3(4, (N + 127) / 128, B), 256, 0, stream>>>(
          h1hf, Wt + (size_t)D * D, hhf, al2, snl, N);
    }
    agg_kernel<<<dim3(N / 4, B), 256, 0, stream>>>(deg, slot, sq_all, snl, hhf,
                                                   last ? nodes : nullptr,
                                                   last ? out : nullptr,
                                                   last ? nullptr : h1hf, l);
  }
}

// Round 9
// 296.233 us; speedup vs baseline: 1.0096x; 1.0096x over previous
//
#include <hip/hip_runtime.h>
#include <hip/hip_fp16.h>
#include <math.h>

constexpr int N = 20000, D = 256, E = 320000, B = 2, L = 2;
constexpr int CAP = 64;  // slot capacity per node; max degree ~34 (balls-in-bins), verified r0==r4

typedef _Float16 f16x8 __attribute__((ext_vector_type(8)));
typedef float f32x4 __attribute__((ext_vector_type(4)));

__device__ __forceinline__ unsigned short f2h(float f) {
  __half h = __float2half(f);  // RNE, v_cvt_f16_f32
  return *(unsigned short*)&h;
}
__device__ __forceinline__ float2 h2f(unsigned int u) {
  __half2 hv = *reinterpret_cast<__half2*>(&u);
  return __half22float2(hv);
}

// ---------------- prep: W transpose->fp16, wa = W@a[:D], zero deg -------------
// blocks 0..511: wt (l = bi>>8, 16x16 tile transpose)
// blocks 512..513: wa (l = bi-512)
// blocks 514..553: zero deg (40000 ints = 10000 uint4)
__global__ __launch_bounds__(256) void prep_kernel(const float* __restrict__ W,
                                                   const float* __restrict__ a,
                                                   unsigned short* __restrict__ Wt,
                                                   float* __restrict__ wa,
                                                   uint4* __restrict__ zbase) {
  int bi = blockIdx.x, tid = threadIdx.x;
  if (bi < 512) {
    __shared__ float t[16][17];
    int l = bi >> 8, rem = bi & 255;
    int by = rem >> 4, bx = rem & 15;  // by: k block, bx: n block
    int tx = tid & 15, ty = tid >> 4;
    t[ty][tx] = W[l * 65536 + (by * 16 + ty) * 256 + bx * 16 + tx];
    __syncthreads();
    Wt[l * 65536 + (bx * 16 + ty) * 256 + by * 16 + tx] = f2h(t[tx][ty]);
  } else if (bi < 514) {
    int l = bi - 512;
    float s = 0.f;
    for (int d = 0; d < D; ++d) s += W[l * 65536 + tid * D + d] * a[l * 2 * D + d];
    wa[l * D + tid] = s;
  } else {
    int zi = (bi - 514) * 256 + tid;
    if (zi < 10000) zbase[zi] = make_uint4(0, 0, 0, 0);
  }
}

// ---------------- MFMA GEMM body (both batches, fp16): Ch = A @ W (fp16 out) ------
// sn partials are PLAIN-STORED per (row, q=bn/64): sn[(z*M+row)*4+q]. No atomics ->
// deterministic; agg sums the 4 partials in fixed order. No zero-init needed.
template <bool F32A>
__device__ __forceinline__ void gemm_body(const void* __restrict__ Av,
                                          const unsigned short* __restrict__ Wt,
                                          unsigned short* __restrict__ Ch,
                                          const float* __restrict__ a2,
                                          float* __restrict__ snp, int M, int z, int bm, int bn,
                                          int tid) {
  __shared__ unsigned short As[128 * 32];  // [m][k]
  __shared__ unsigned short Bs[64 * 32];   // [n][k]
  unsigned short* Cz = Ch + (size_t)z * M * 256;
  float* snz = snp + (size_t)z * M * 4;
  int q = bn >> 6;
  int wv = tid >> 6, lane = tid & 63;
  int lm = lane & 15, lq = lane >> 4;
  f32x4 acc[2][4] = {};

  for (int k0 = 0; k0 < 256; k0 += 32) {
    int m = tid >> 1, kb = (tid & 1) << 4;
    if (bm + m < M) {
      if constexpr (F32A) {
        const float* ap = (const float*)Av + (size_t)z * M * 256 + (size_t)(bm + m) * 256 + k0 + kb;
        float4 v0 = ((const float4*)ap)[0];
        float4 v1 = ((const float4*)ap)[1];
        float4 v2 = ((const float4*)ap)[2];
        float4 v3 = ((const float4*)ap)[3];
        unsigned short t[16] = {f2h(v0.x), f2h(v0.y), f2h(v0.z), f2h(v0.w),
                                f2h(v1.x), f2h(v1.y), f2h(v1.z), f2h(v1.w),
                                f2h(v2.x), f2h(v2.y), f2h(v2.z), f2h(v2.w),
                                f2h(v3.x), f2h(v3.y), f2h(v3.z), f2h(v3.w)};
        *(uint4*)&As[m * 32 + kb] = *(uint4*)t;
        *(uint4*)&As[m * 32 + kb + 8] = *(uint4*)(t + 8);
      } else {
        const unsigned short* ap =
            (const unsigned short*)Av + (size_t)z * M * 256 + (size_t)(bm + m) * 256 + k0 + kb;
        *(uint4*)&As[m * 32 + kb] = *(const uint4*)ap;
        *(uint4*)&As[m * 32 + kb + 8] = *(const uint4*)(ap + 8);
      }
    } else {
      uint4 z4 = make_uint4(0, 0, 0, 0);
      *(uint4*)&As[m * 32 + kb] = z4;
      *(uint4*)&As[m * 32 + kb + 8] = z4;
    }
    int nn = tid >> 2, kb2 = (tid & 3) << 3;
    *(uint4*)&Bs[nn * 32 + kb2] = *(const uint4*)(Wt + (size_t)(bn + nn) * 256 + k0 + kb2);
    __syncthreads();

    f16x8 af0 = *(const f16x8*)&As[(wv * 32 + lm) * 32 + lq * 8];
    f16x8 af1 = *(const f16x8*)&As[(wv * 32 + 16 + lm) * 32 + lq * 8];
#pragma unroll
    for (int nf = 0; nf < 4; ++nf) {
      f16x8 bfr = *(const f16x8*)&Bs[(nf * 16 + lm) * 32 + lq * 8];
      acc[0][nf] = __builtin_amdgcn_mfma_f32_16x16x32_f16(af0, bfr, acc[0][nf], 0, 0, 0);
      acc[1][nf] = __builtin_amdgcn_mfma_f32_16x16x32_f16(af1, bfr, acc[1][nf], 0, 0, 0);
    }
    __syncthreads();
  }

  float a2v[4];
#pragma unroll
  for (int nf = 0; nf < 4; ++nf) a2v[nf] = a2[bn + nf * 16 + lm];
#pragma unroll
  for (int f = 0; f < 2; ++f) {
#pragma unroll
    for (int r = 0; r < 4; ++r) {
      int row = bm + wv * 32 + f * 16 + lq * 4 + r;
      if (row < M) {
        float partial = 0.f;
#pragma unroll
        for (int nf = 0; nf < 4; ++nf) {
          float v = acc[f][nf][r];
          Cz[(size_t)row * 256 + bn + nf * 16 + lm] = f2h(v);  // fp16 intermediate
          partial += v * a2v[nf];
        }
        partial += __shfl_xor(partial, 1);
        partial += __shfl_xor(partial, 2);
        partial += __shfl_xor(partial, 4);
        partial += __shfl_xor(partial, 8);
        if (lm == 0) snz[((size_t)row << 2) | q] = partial;  // deterministic, race-free
      }
    }
  }
}

// ---------------- mega0: scatter + gemm layer-0 + sq fused (all mutually independent) -------
__global__ __launch_bounds__(256) void mega0_kernel(const float* __restrict__ nodes,
                                                    const unsigned short* __restrict__ Wt,
                                                    unsigned short* __restrict__ hhf,
                                                    const float* __restrict__ a2l0,
                                                    float* __restrict__ sn0,
                                                    const float* __restrict__ xq,
                                                    const float* __restrict__ wa,
                                                    float* __restrict__ sq,
                                                    const int* __restrict__ edges,
                                                    int* __restrict__ deg,
                                                    int* __restrict__ slot) {
  int bi = blockIdx.x, tid = threadIdx.x;
  if (bi < 625) {
    int ebase = bi * 1024 + tid;  // 625*1024 = B*E = 640,000 exact
    int s4[4], d4[4];
#pragma unroll
    for (int q = 0; q < 4; ++q) {
      int e = ebase + q * 256;
      int b = (e >= E) ? 1 : 0;
      s4[q] = edges[(size_t)b * E + e];
      d4[q] = edges[(size_t)(b + 1) * E + e];
    }
#pragma unroll
    for (int q = 0; q < 4; ++q) {
      int e = ebase + q * 256;
      int b = (e >= E) ? 1 : 0;
      int nb = b * N + s4[q];
      int pos = atomicAdd(&deg[nb], 1);
      if (pos < CAP) slot[((size_t)nb << 6) + pos] = d4[q];
    }
  } else if (bi < 1881) {
    int g = bi - 625;           // 0..1255
    int z = g / 628;            // 628 = 157 * 4
    int rem = g % 628;
    int bm = (rem >> 2) * 128;  // 157 m-blocks (157*128 = 20096 >= N, tail guarded)
    int bn = (rem & 3) * 64;
    gemm_body<true>(nodes, Wt, hhf, a2l0, sn0, N, z, bm, bn, tid);
  } else {
    int sqb = bi - 1881;
    int b = (sqb >= 5000) ? 1 : 0;
    int blk = sqb - b * 5000;
    int wave = blk * 4 + (tid >> 6);
    int lane = tid & 63;
    const float4 xv = *(const float4*)(xq + ((size_t)b * N + wave) * D + (lane << 2));
    const float4 w0 = *(const float4*)(wa + (lane << 2));
    const float4 w1 = *(const float4*)(wa + D + (lane << 2));
    float s0 = xv.x * w0.x + xv.y * w0.y + xv.z * w0.z + xv.w * w0.w;
    float s1 = xv.x * w1.x + xv.y * w1.y + xv.z * w1.z + xv.w * w1.w;
    for (int off = 32; off; off >>= 1) {
      s0 += __shfl_down(s0, off);
      s1 += __shfl_down(s1, off);
    }
    if (lane == 0) {
      sq[(b * 2 + 0) * N + wave] = s0;
      sq[(b * 2 + 1) * N + wave] = s1;
    }
  }
}

// ---------------- gemm layer-1 (fp16 A = h1) ----------------
__global__ __launch_bounds__(256) void gemm_l1(const unsigned short* __restrict__ A,
                                               const unsigned short* __restrict__ Wt,
                                               unsigned short* __restrict__ Ch,
                                               const float* __restrict__ a2,
                                               float* __restrict__ sn, int M) {
  gemm_body<false>(A, Wt, Ch, a2, sn, M, blockIdx.z, blockIdx.y * 128, blockIdx.x * 64,
                   threadIdx.x);
}

// ---------------- fused weight + aggregation: ONE WAVE per node, DETERMINISTIC ----------
// Slot arrival order is nondeterministic (atomics); we canonicalize with a 64-lane
// bitonic sort of idx by value (sentinel INT_MAX for lanes >= cnt -> valid entries end
// up in lanes 0..cnt-1, ascending). Duplicate dst values are identical terms, so tie
// order is irrelevant. All downstream sums then depend only on slot CONTENT ->
// bit-identical output on every graph replay. sn partials summed in fixed order.
__global__ __launch_bounds__(256) void agg_kernel(const int* __restrict__ deg,
                                                  const int* __restrict__ slot,
                                                  const float* __restrict__ sq_all,
                                                  const float* __restrict__ snp,
                                                  const unsigned short* __restrict__ hhf,
                                                  const float* __restrict__ resid,
                                                  float* __restrict__ outf,
                                                  unsigned short* __restrict__ outh, int l) {
  int b = blockIdx.y;
  int tid = threadIdx.x, wv = tid >> 6, lane = tid & 63;
  int node = blockIdx.x * 4 + wv;
  int eg = lane >> 5, dl = lane & 31;
  const float4* snb = (const float4*)snp + (size_t)b * N;
  const unsigned short* hb = hhf + (size_t)b * N * 256;
  int nb = b * N + node;
  int cnt = min(deg[nb], CAP);
  const int* sl = slot + ((size_t)nb << 6);
  float sqv = sq_all[((b << 1) + l) * N + node];
  // load (in-bounds for all 64 lanes); sentinel for invalid lanes
  int key = (lane < cnt) ? sl[lane] : 0x7fffffff;
  // 64-lane bitonic sort ascending (21 compare-exchange stages)
#pragma unroll
  for (int k = 2; k <= 64; k <<= 1) {
#pragma unroll
    for (int j = k >> 1; j > 0; j >>= 1) {
      int o = __shfl_xor(key, j);
      bool keepMin = (((lane & k) == 0) == ((lane & j) == 0));
      key = keepMin ? min(key, o) : max(key, o);
    }
  }
  int idx = (lane < cnt) ? key : 0;
  float snv = 0.f;
  if (lane < cnt) {
    float4 sv = snb[idx];
    snv = (sv.x + sv.y) + (sv.z + sv.w);  // fixed-order partial sum
  }
  int nj = (cnt - eg + 1) >> 1;  // edges this half-wave handles (j = eg, eg+2, ...)
  // issue first gather batch from idx alone (overlaps the snv/exp chain below)
  uint4 hv[4];
#pragma unroll
  for (int u = 0; u < 4; ++u) {
    int dsti = __shfl(idx, eg + 2 * u);  // <= 7, in range
    if (u < nj) hv[u] = *(const uint4*)(hb + (size_t)dsti * 256 + (dl << 3));
  }
  float s = sqv + snv;
  float lr = (s >= 0.f) ? s : 0.2f * s;
  float w = (lane < cnt) ? __expf(-lr) : 0.f;
  float wsum = w;
  float acc[8] = {};
  for (int u0 = 0; u0 < nj; u0 += 4) {
    uint4 hn[4];
#pragma unroll
    for (int u = 0; u < 4; ++u) {  // prefetch next batch
      int uu = u0 + 4 + u;
      int js = eg + 2 * uu;
      js = (js < 63) ? js : 63;  // clamp (result unused when uu >= nj)
      int dsti = __shfl(idx, js);
      if (uu < nj) hn[u] = *(const uint4*)(hb + (size_t)dsti * 256 + (dl << 3));
    }
#pragma unroll
    for (int u = 0; u < 4; ++u) {
      int uu = u0 + u;
      if (uu < nj) {
        float wj = __shfl(w, eg + 2 * uu);
        float2 f0 = h2f(hv[u].x), f1 = h2f(hv[u].y), f2 = h2f(hv[u].z), f3 = h2f(hv[u].w);
        acc[0] = fmaf(wj, f0.x, acc[0]);
        acc[1] = fmaf(wj, f0.y, acc[1]);
        acc[2] = fmaf(wj, f1.x, acc[2]);
        acc[3] = fmaf(wj, f1.y, acc[3]);
        acc[4] = fmaf(wj, f2.x, acc[4]);
        acc[5] = fmaf(wj, f2.y, acc[5]);
        acc[6] = fmaf(wj, f3.x, acc[6]);
        acc[7] = fmaf(wj, f3.y, acc[7]);
      }
    }
#pragma unroll
    for (int u = 0; u < 4; ++u) hv[u] = hn[u];
  }
  // full-wave rowsum (same value in every lane; fixed tree -> deterministic)
  for (int off = 32; off; off >>= 1) wsum += __shfl_xor(wsum, off);
  // merge the two half-wave edge partitions; every lane ends with the full sum
#pragma unroll
  for (int i = 0; i < 8; ++i) acc[i] += __shfl_xor(acc[i], 32);
  float inv = (wsum > 0.f) ? 1.f / wsum : 0.f;
  float o0 = (eg ? acc[4] : acc[0]) * inv;
  float o1 = (eg ? acc[5] : acc[1]) * inv;
  float o2 = (eg ? acc[6] : acc[2]) * inv;
  float o3 = (eg ? acc[7] : acc[3]) * inv;
  size_t rowoff = ((size_t)b * N + node) * 256 + (dl << 3) + (eg << 2);
  if (outh) {
    unsigned short t[4] = {f2h(o0), f2h(o1), f2h(o2), f2h(o3)};
    *(uint2*)(outh + rowoff) = *(uint2*)t;
  } else {
    const float4 rv = *(const float4*)(resid + rowoff);
    *(float4*)(outf + rowoff) = make_float4(o0 + rv.x, o1 + rv.y, o2 + rv.z, o3 + rv.w);
  }
}

extern "C" void kernel_launch(void* const* d_in, const int* in_sizes, int n_in,
                              void* d_out, int out_size, void* d_ws, size_t ws_size,
                              hipStream_t stream) {
  const float* nodes = (const float*)d_in[0];
  const float* nodesq = (const float*)d_in[1];
  const float* W = (const float*)d_in[2];
  const float* a = (const float*)d_in[3];
  const int* edges = (const int*)d_in[4];
  float* out = (float*)d_out;

  const size_t ND = (size_t)N * D;
  unsigned short* hhf = (unsigned short*)d_ws;  // B*N*D  (GEMM output h_proj, fp16)
  unsigned short* h1hf = hhf + (size_t)B * ND;  // B*N*D  (layer-0 agg output, fp16)
  unsigned short* Wt = h1hf + (size_t)B * ND;   // L*D*D (fp16)
  int* deg = (int*)(Wt + (size_t)L * D * D);    // B*N (zeroed by prep)
  float* sn0 = (float*)(deg + B * N);           // B*N*4 partials (fully overwritten)
  float* sn1 = sn0 + (size_t)B * N * 4;         // B*N*4 partials
  float* sq_all = sn1 + (size_t)B * N * 4;      // B*L*N
  float* wa = sq_all + (size_t)B * L * N;       // L*D
  int* slot = (int*)(wa + L * D);               // B*N*CAP ints (10.24 MB)

  prep_kernel<<<554, 256, 0, stream>>>(W, a, Wt, wa, (uint4*)deg);
  // scatter + gemm layer-0 + sq in one launch: gemm/sq hide the scatter's
  // random-access memory wall; safe now that agg canonicalizes slot order.
  mega0_kernel<<<11881, 256, 0, stream>>>(nodes, Wt, hhf, a + D, sn0, nodesq, wa, sq_all,
                                          edges, deg, slot);
  agg_kernel<<<dim3(N / 4, B), 256, 0, stream>>>(deg, slot, sq_all, sn0, hhf, nullptr,
                                                 nullptr, h1hf, 0);
  gemm_l1<<<dim3(4, (N + 127) / 128, B), 256, 0, stream>>>(h1hf, Wt + (size_t)D * D, hhf,
                                                           a + 3 * D, sn1, N);
  agg_kernel<<<dim3(N / 4, B), 256, 0, stream>>>(deg, slot, sq_all, sn1, hhf, nodes, out,
                                                 nullptr, 1);
}

// Round 10
// 291.544 us; speedup vs baseline: 1.0259x; 1.0161x over previous
//
#include <hip/hip_runtime.h>
#include <hip/hip_fp16.h>
#include <math.h>

constexpr int N = 20000, D = 256, E = 320000, B = 2, L = 2;
constexpr int CAP = 64;   // slot capacity per node; max degree ~45 < 64
constexpr int LDA = 40;   // padded LDS row stride (shorts): kills 8-way bank conflicts

typedef _Float16 f16x8 __attribute__((ext_vector_type(8)));
typedef float f32x4 __attribute__((ext_vector_type(4)));

__device__ __forceinline__ unsigned short f2h(float f) {
  __half h = __float2half(f);  // RNE, v_cvt_f16_f32
  return *(unsigned short*)&h;
}
__device__ __forceinline__ float2 h2f(unsigned int u) {
  __half2 hv = *reinterpret_cast<__half2*>(&u);
  return __half22float2(hv);
}

// ---------------- prep: W transpose->fp16, wa = W@a[:D], zero deg -------------
__global__ __launch_bounds__(256) void prep_kernel(const float* __restrict__ W,
                                                   const float* __restrict__ a,
                                                   unsigned short* __restrict__ Wt,
                                                   float* __restrict__ wa,
                                                   uint4* __restrict__ zbase) {
  int bi = blockIdx.x, tid = threadIdx.x;
  if (bi < 512) {
    __shared__ float t[16][17];
    int l = bi >> 8, rem = bi & 255;
    int by = rem >> 4, bx = rem & 15;  // by: k block, bx: n block
    int tx = tid & 15, ty = tid >> 4;
    t[ty][tx] = W[l * 65536 + (by * 16 + ty) * 256 + bx * 16 + tx];
    __syncthreads();
    Wt[l * 65536 + (bx * 16 + ty) * 256 + by * 16 + tx] = f2h(t[tx][ty]);
  } else if (bi < 514) {
    int l = bi - 512;
    float s = 0.f;
    for (int d = 0; d < D; ++d) s += W[l * 65536 + tid * D + d] * a[l * 2 * D + d];
    wa[l * D + tid] = s;
  } else {
    int zi = (bi - 514) * 256 + tid;
    if (zi < 10000) zbase[zi] = make_uint4(0, 0, 0, 0);
  }
}

// ---------------- MFMA GEMM body (both batches, fp16): Ch = A @ W (fp16 out) ------
// sn partials PLAIN-STORED per (row, q=bn/64) -> deterministic, no atomics.
// LDS rows padded to LDA=40 shorts: ds_read_b128 conflicts 8-way -> 2-way (free).
template <bool F32A>
__device__ __forceinline__ void gemm_body(const void* __restrict__ Av,
                                          const unsigned short* __restrict__ Wt,
                                          unsigned short* __restrict__ Ch,
                                          const float* __restrict__ a2,
                                          float* __restrict__ snp, int M, int z, int bm, int bn,
                                          int tid) {
  __shared__ unsigned short As[128 * LDA];  // [m][k] padded
  __shared__ unsigned short Bs[64 * LDA];   // [n][k] padded
  unsigned short* Cz = Ch + (size_t)z * M * 256;
  float* snz = snp + (size_t)z * M * 4;
  int q = bn >> 6;
  int wv = tid >> 6, lane = tid & 63;
  int lm = lane & 15, lq = lane >> 4;
  f32x4 acc[2][4] = {};

  for (int k0 = 0; k0 < 256; k0 += 32) {
    int m = tid >> 1, kb = (tid & 1) << 4;
    if (bm + m < M) {
      if constexpr (F32A) {
        const float* ap = (const float*)Av + (size_t)z * M * 256 + (size_t)(bm + m) * 256 + k0 + kb;
        float4 v0 = ((const float4*)ap)[0];
        float4 v1 = ((const float4*)ap)[1];
        float4 v2 = ((const float4*)ap)[2];
        float4 v3 = ((const float4*)ap)[3];
        unsigned short t[16] = {f2h(v0.x), f2h(v0.y), f2h(v0.z), f2h(v0.w),
                                f2h(v1.x), f2h(v1.y), f2h(v1.z), f2h(v1.w),
                                f2h(v2.x), f2h(v2.y), f2h(v2.z), f2h(v2.w),
                                f2h(v3.x), f2h(v3.y), f2h(v3.z), f2h(v3.w)};
        *(uint4*)&As[m * LDA + kb] = *(uint4*)t;
        *(uint4*)&As[m * LDA + kb + 8] = *(uint4*)(t + 8);
      } else {
        const unsigned short* ap =
            (const unsigned short*)Av + (size_t)z * M * 256 + (size_t)(bm + m) * 256 + k0 + kb;
        *(uint4*)&As[m * LDA + kb] = *(const uint4*)ap;
        *(uint4*)&As[m * LDA + kb + 8] = *(const uint4*)(ap + 8);
      }
    } else {
      uint4 z4 = make_uint4(0, 0, 0, 0);
      *(uint4*)&As[m * LDA + kb] = z4;
      *(uint4*)&As[m * LDA + kb + 8] = z4;
    }
    int nn = tid >> 2, kb2 = (tid & 3) << 3;
    *(uint4*)&Bs[nn * LDA + kb2] = *(const uint4*)(Wt + (size_t)(bn + nn) * 256 + k0 + kb2);
    __syncthreads();

    f16x8 af0 = *(const f16x8*)&As[(wv * 32 + lm) * LDA + lq * 8];
    f16x8 af1 = *(const f16x8*)&As[(wv * 32 + 16 + lm) * LDA + lq * 8];
#pragma unroll
    for (int nf = 0; nf < 4; ++nf) {
      f16x8 bfr = *(const f16x8*)&Bs[(nf * 16 + lm) * LDA + lq * 8];
      acc[0][nf] = __builtin_amdgcn_mfma_f32_16x16x32_f16(af0, bfr, acc[0][nf], 0, 0, 0);
      acc[1][nf] = __builtin_amdgcn_mfma_f32_16x16x32_f16(af1, bfr, acc[1][nf], 0, 0, 0);
    }
    __syncthreads();
  }

  float a2v[4];
#pragma unroll
  for (int nf = 0; nf < 4; ++nf) a2v[nf] = a2[bn + nf * 16 + lm];
#pragma unroll
  for (int f = 0; f < 2; ++f) {
#pragma unroll
    for (int r = 0; r < 4; ++r) {
      int row = bm + wv * 32 + f * 16 + lq * 4 + r;
      if (row < M) {
        float partial = 0.f;
#pragma unroll
        for (int nf = 0; nf < 4; ++nf) {
          float v = acc[f][nf][r];
          Cz[(size_t)row * 256 + bn + nf * 16 + lm] = f2h(v);  // fp16 intermediate
          partial += v * a2v[nf];
        }
        partial += __shfl_xor(partial, 1);
        partial += __shfl_xor(partial, 2);
        partial += __shfl_xor(partial, 4);
        partial += __shfl_xor(partial, 8);
        if (lm == 0) snz[((size_t)row << 2) | q] = partial;  // deterministic, race-free
      }
    }
  }
}

// ---------------- mega0: XCD-sharded scatter + gemm layer-0 + sq ----------------
// Scatter blocks bi<5000: shard = bi&7 (under round-robin blockIdx->XCD, all atomics
// to a shard's deg/slot lines issue from ONE XCD -> no cross-XCD line ping-pong);
// slice = bi>>3 reads 1024 edges, filters nb in [shard*5000, shard*5000+5000).
// Edges (5MB) are L3-resident across the 8 shard passes. Slot is ushort (dst<20000).
__global__ __launch_bounds__(256) void mega0_kernel(const float* __restrict__ nodes,
                                                    const unsigned short* __restrict__ Wt,
                                                    unsigned short* __restrict__ hhf,
                                                    const float* __restrict__ a2l0,
                                                    float* __restrict__ sn0,
                                                    const float* __restrict__ xq,
                                                    const float* __restrict__ wa,
                                                    float* __restrict__ sq,
                                                    const int* __restrict__ edges,
                                                    int* __restrict__ deg,
                                                    unsigned short* __restrict__ slot) {
  int bi = blockIdx.x, tid = threadIdx.x;
  if (bi < 5000) {
    int shard = bi & 7, slice = bi >> 3;
    int lo = shard * 5000;
    int ebase = slice * 1024 + tid;  // 625*1024 = B*E = 640,000 exact
#pragma unroll
    for (int qq = 0; qq < 4; ++qq) {
      int e = ebase + qq * 256;
      int b = (e >= E) ? 1 : 0;
      int s = edges[(size_t)b * E + e];
      int d = edges[(size_t)(b + 1) * E + e];
      int nb = b * N + s;
      if ((unsigned)(nb - lo) < 5000u) {
        int pos = atomicAdd(&deg[nb], 1);
        if (pos < CAP) slot[((size_t)nb << 6) + pos] = (unsigned short)d;
      }
    }
  } else if (bi < 6256) {
    int g = bi - 5000;          // 0..1255
    int z = g / 628;            // 628 = 157 * 4
    int rem = g % 628;
    int bm = (rem >> 2) * 128;  // 157 m-blocks (157*128 = 20096 >= N, tail guarded)
    int bn = (rem & 3) * 64;
    gemm_body<true>(nodes, Wt, hhf, a2l0, sn0, N, z, bm, bn, tid);
  } else {
    int sqb = bi - 6256;
    int b = (sqb >= 5000) ? 1 : 0;
    int blk = sqb - b * 5000;
    int wave = blk * 4 + (tid >> 6);
    int lane = tid & 63;
    const float4 xv = *(const float4*)(xq + ((size_t)b * N + wave) * D + (lane << 2));
    const float4 w0 = *(const float4*)(wa + (lane << 2));
    const float4 w1 = *(const float4*)(wa + D + (lane << 2));
    float s0 = xv.x * w0.x + xv.y * w0.y + xv.z * w0.z + xv.w * w0.w;
    float s1 = xv.x * w1.x + xv.y * w1.y + xv.z * w1.z + xv.w * w1.w;
    for (int off = 32; off; off >>= 1) {
      s0 += __shfl_down(s0, off);
      s1 += __shfl_down(s1, off);
    }
    if (lane == 0) {
      sq[(b * 2 + 0) * N + wave] = s0;
      sq[(b * 2 + 1) * N + wave] = s1;
    }
  }
}

// ---------------- gemm layer-1 (fp16 A = h1) ----------------
__global__ __launch_bounds__(256) void gemm_l1(const unsigned short* __restrict__ A,
                                               const unsigned short* __restrict__ Wt,
                                               unsigned short* __restrict__ Ch,
                                               const float* __restrict__ a2,
                                               float* __restrict__ sn, int M) {
  gemm_body<false>(A, Wt, Ch, a2, sn, M, blockIdx.z, blockIdx.y * 128, blockIdx.x * 64,
                   threadIdx.x);
}

// ---------------- fused weight + aggregation: ONE WAVE per node, DETERMINISTIC ----------
// Canonicalizes nondeterministic slot arrival order with a 64-lane bitonic sort of idx
// by value (INT_MAX sentinel). Output is a pure function of slot CONTENT -> bit-identical
// on every replay. sn partials summed in fixed order.
__global__ __launch_bounds__(256) void agg_kernel(const int* __restrict__ deg,
                                                  const unsigned short* __restrict__ slot,
                                                  const float* __restrict__ sq_all,
                                                  const float* __restrict__ snp,
                                                  const unsigned short* __restrict__ hhf,
                                                  const float* __restrict__ resid,
                                                  float* __restrict__ outf,
                                                  unsigned short* __restrict__ outh, int l) {
  int b = blockIdx.y;
  int tid = threadIdx.x, wv = tid >> 6, lane = tid & 63;
  int node = blockIdx.x * 4 + wv;
  int eg = lane >> 5, dl = lane & 31;
  const float4* snb = (const float4*)snp + (size_t)b * N;
  const unsigned short* hb = hhf + (size_t)b * N * 256;
  int nb = b * N + node;
  int cnt = min(deg[nb], CAP);
  const unsigned short* sl = slot + ((size_t)nb << 6);
  float sqv = sq_all[((b << 1) + l) * N + node];
  int key = (lane < cnt) ? (int)sl[lane] : 0x7fffffff;
  // 64-lane bitonic sort ascending (21 compare-exchange stages)
#pragma unroll
  for (int k = 2; k <= 64; k <<= 1) {
#pragma unroll
    for (int j = k >> 1; j > 0; j >>= 1) {
      int o = __shfl_xor(key, j);
      bool keepMin = (((lane & k) == 0) == ((lane & j) == 0));
      key = keepMin ? min(key, o) : max(key, o);
    }
  }
  int idx = (lane < cnt) ? key : 0;
  float snv = 0.f;
  if (lane < cnt) {
    float4 sv = snb[idx];
    snv = (sv.x + sv.y) + (sv.z + sv.w);  // fixed-order partial sum
  }
  int nj = (cnt - eg + 1) >> 1;  // edges this half-wave handles (j = eg, eg+2, ...)
  uint4 hv[4];
#pragma unroll
  for (int u = 0; u < 4; ++u) {
    int dsti = __shfl(idx, eg + 2 * u);
    if (u < nj) hv[u] = *(const uint4*)(hb + (size_t)dsti * 256 + (dl << 3));
  }
  float s = sqv + snv;
  float lr = (s >= 0.f) ? s : 0.2f * s;
  float w = (lane < cnt) ? __expf(-lr) : 0.f;
  float wsum = w;
  float acc[8] = {};
  for (int u0 = 0; u0 < nj; u0 += 4) {
    uint4 hn[4];
#pragma unroll
    for (int u = 0; u < 4; ++u) {  // prefetch next batch
      int uu = u0 + 4 + u;
      int js = eg + 2 * uu;
      js = (js < 63) ? js : 63;
      int dsti = __shfl(idx, js);
      if (uu < nj) hn[u] = *(const uint4*)(hb + (size_t)dsti * 256 + (dl << 3));
    }
#pragma unroll
    for (int u = 0; u < 4; ++u) {
      int uu = u0 + u;
      if (uu < nj) {
        float wj = __shfl(w, eg + 2 * uu);
        float2 f0 = h2f(hv[u].x), f1 = h2f(hv[u].y), f2 = h2f(hv[u].z), f3 = h2f(hv[u].w);
        acc[0] = fmaf(wj, f0.x, acc[0]);
        acc[1] = fmaf(wj, f0.y, acc[1]);
        acc[2] = fmaf(wj, f1.x, acc[2]);
        acc[3] = fmaf(wj, f1.y, acc[3]);
        acc[4] = fmaf(wj, f2.x, acc[4]);
        acc[5] = fmaf(wj, f2.y, acc[5]);
        acc[6] = fmaf(wj, f3.x, acc[6]);
        acc[7] = fmaf(wj, f3.y, acc[7]);
      }
    }
#pragma unroll
    for (int u = 0; u < 4; ++u) hv[u] = hn[u];
  }
  for (int off = 32; off; off >>= 1) wsum += __shfl_xor(wsum, off);
#pragma unroll
  for (int i = 0; i < 8; ++i) acc[i] += __shfl_xor(acc[i], 32);
  float inv = (wsum > 0.f) ? 1.f / wsum : 0.f;
  float o0 = (eg ? acc[4] : acc[0]) * inv;
  float o1 = (eg ? acc[5] : acc[1]) * inv;
  float o2 = (eg ? acc[6] : acc[2]) * inv;
  float o3 = (eg ? acc[7] : acc[3]) * inv;
  size_t rowoff = ((size_t)b * N + node) * 256 + (dl << 3) + (eg << 2);
  if (outh) {
    unsigned short t[4] = {f2h(o0), f2h(o1), f2h(o2), f2h(o3)};
    *(uint2*)(outh + rowoff) = *(uint2*)t;
  } else {
    const float4 rv = *(const float4*)(resid + rowoff);
    *(float4*)(outf + rowoff) = make_float4(o0 + rv.x, o1 + rv.y, o2 + rv.z, o3 + rv.w);
  }
}

extern "C" void kernel_launch(void* const* d_in, const int* in_sizes, int n_in,
                              void* d_out, int out_size, void* d_ws, size_t ws_size,
                              hipStream_t stream) {
  const float* nodes = (const float*)d_in[0];
  const float* nodesq = (const float*)d_in[1];
  const float* W = (const float*)d_in[2];
  const float* a = (const float*)d_in[3];
  const int* edges = (const int*)d_in[4];
  float* out = (float*)d_out;

  const size_t ND = (size_t)N * D;
  unsigned short* hhf = (unsigned short*)d_ws;  // B*N*D  (GEMM output h_proj, fp16)
  unsigned short* h1hf = hhf + (size_t)B * ND;  // B*N*D  (layer-0 agg output, fp16)
  unsigned short* Wt = h1hf + (size_t)B * ND;   // L*D*D (fp16)
  int* deg = (int*)(Wt + (size_t)L * D * D);    // B*N (zeroed by prep)
  float* sn0 = (float*)(deg + B * N);           // B*N*4 partials (fully overwritten)
  float* sn1 = sn0 + (size_t)B * N * 4;         // B*N*4 partials
  float* sq_all = sn1 + (size_t)B * N * 4;      // B*L*N
  float* wa = sq_all + (size_t)B * L * N;       // L*D
  unsigned short* slot = (unsigned short*)(wa + L * D);  // B*N*CAP ushorts (5.12 MB)

  prep_kernel<<<554, 256, 0, stream>>>(W, a, Wt, wa, (uint4*)deg);
  mega0_kernel<<<16256, 256, 0, stream>>>(nodes, Wt, hhf, a + D, sn0, nodesq, wa, sq_all,
                                          edges, deg, slot);
  agg_kernel<<<dim3(N / 4, B), 256, 0, stream>>>(deg, slot, sq_all, sn0, hhf, nullptr,
                                                 nullptr, h1hf, 0);
  gemm_l1<<<dim3(4, (N + 127) / 128, B), 256, 0, stream>>>(h1hf, Wt + (size_t)D * D, hhf,
                                                           a + 3 * D, sn1, N);
  agg_kernel<<<dim3(N / 4, B), 256, 0, stream>>>(deg, slot, sq_all, sn1, hhf, nodes, out,
                                                 nullptr, 1);
}